// Round 4
// baseline (621.852 us; speedup 1.0000x reference)
//
#include <hip/hip_runtime.h>

// DecoupledSOLOHead: SOLO mask decode + Matrix NMS (gaussian), MI355X/gfx950.
//
// R4 changes vs R3 (passed, 135.1 us; harness fills ~41us + restore ~19us are a
// fixed ~60us floor; our 4 kernels ~70us):
//  - maskgen inner mapping swapped: lane = pixel, wave iterates dets. Per det the
//    wave reads a uniform row (64 consecutive floats -> 2-way bank alias = free)
//    vs R3's per-thread random-row gather (~4-6-way conflicts, 128 scalar reads).
//  - cnt from __popcll(ballot) (no lane reduce); ssum via 6-step shfl.
//  - per-(tile,det) stats atomicAdd'ed into float[500] accumulators ->
//    finalize kernel + 3.8 MB partial arrays deleted; 4 KB memset node instead.
//  - score computation folded into decay kernel.

#define N_DET 500
#define HW    (200 * 304)        // 60800
#define TILE  64
#define NT    (HW / TILE)        // 950 tiles, exact
#define NWORDS NT                // one u64 word per det per tile
#define NW2   (NWORDS / 2)       // 475 ulonglong2 granules
#define LSTR  65                 // LDS row stride (floats)
#define MASK_THR 0.005f
#define SIGMA 2.0f

// ---------------- Kernel A: pixel-tiled broadcast decode + bit-pack ------------
__global__ __launch_bounds__(512) void maskgen_kernel(
    const float* __restrict__ seg_x, const float* __restrict__ seg_y,
    const int* __restrict__ x_inds, const int* __restrict__ y_inds,
    unsigned long long* __restrict__ packed,   // [N_DET][NT] det-major
    float* __restrict__ ssum_acc,              // [N_DET] pre-zeroed
    float* __restrict__ cnt_acc)               // [N_DET] pre-zeroed
{
    __shared__ float   sx[128 * LSTR];         // 33,280 B
    __shared__ float   sy[128 * LSTR];         // 33,280 B
    __shared__ ushort2 s_ind[N_DET];           //  2,000 B
    const int t    = blockIdx.x;
    const int tid  = threadIdx.x;
    const int lane = tid & 63;
    const int wav  = tid >> 6;                 // 0..7
    const int base = t * TILE;

    // stage 128 rows x 64 px of each operand (each element read once chip-wide)
    for (int e = tid; e < 128 * 16; e += 512) {
        const int r  = e >> 4;
        const int c4 = (e & 15) << 2;
        const float4 vx = *(const float4*)(seg_x + (size_t)r * HW + base + c4);
        const float4 vy = *(const float4*)(seg_y + (size_t)r * HW + base + c4);
        float* dx = sx + r * LSTR + c4;
        float* dy = sy + r * LSTR + c4;
        dx[0] = vx.x; dx[1] = vx.y; dx[2] = vx.z; dx[3] = vx.w;
        dy[0] = vy.x; dy[1] = vy.y; dy[2] = vy.z; dy[3] = vy.w;
    }
    for (int d = tid; d < N_DET; d += 512)
        s_ind[d] = make_ushort2((unsigned short)x_inds[d], (unsigned short)y_inds[d]);
    __syncthreads();

    // wave per det: uniform-row LDS reads (2-way alias = free), ballot pack
    for (int d = wav; d < N_DET; d += 8) {
        const ushort2 xy = s_ind[d];           // wave-uniform broadcast read
        const float v = sx[xy.x * LSTR + lane] * sy[xy.y * LSTR + lane];
        const bool  h = v > MASK_THR;
        const unsigned long long m = __ballot(h);
        float s = h ? v : 0.0f;
        #pragma unroll
        for (int off = 32; off; off >>= 1) s += __shfl_down(s, off);
        if (lane == 0) {
            packed[(size_t)d * NT + t] = m;
            atomicAdd(ssum_acc + d, s);
            atomicAdd(cnt_acc + d, (float)__popcll(m));
        }
    }
}

// ---------------- Kernel B: same-class pairwise IoU via popcount ---------------
__global__ __launch_bounds__(256) void pair_iou_kernel(
    const unsigned long long* __restrict__ packed,
    const float* __restrict__ sum_masks,   // = cnt_acc (exact integer-valued)
    const int* __restrict__ labels,
    float* __restrict__ d2col,    // [N][N] col-major: d2col[j*N+i] = decay_iou^2
    float* __restrict__ comp2)    // [N] comp_iou^2
{
    const int j   = blockIdx.x;
    const int tid = threadIdx.x;
    const int lane = tid & 63, wav = tid >> 6;

    __shared__ int   s_lab[N_DET];
    __shared__ float s_sm[N_DET];
    __shared__ int   s_list[N_DET];
    __shared__ int   s_cnt;
    __shared__ float s_max[4];

    if (tid == 0) s_cnt = 0;
    for (int i = tid; i < N_DET; i += 256) {
        s_lab[i] = labels[i];
        s_sm[i]  = sum_masks[i];
        d2col[(size_t)j * N_DET + i] = 0.0f;   // ws is re-poisoned each launch
    }
    __syncthreads();

    const int   lj = s_lab[j];
    const float sj = s_sm[j];
    for (int i = tid; i < j; i += 256)
        if (s_lab[i] == lj) { const int p = atomicAdd(&s_cnt, 1); s_list[p] = i; }
    __syncthreads();
    const int cnt = s_cnt;

    // preload j's mask fragment into registers (475 ulonglong2 across 64 lanes)
    const ulonglong2* __restrict__ pj2 = (const ulonglong2*)(packed + (size_t)j * NWORDS);
    ulonglong2 bj[8];
    #pragma unroll
    for (int t = 0; t < 8; ++t) {
        const int w = lane + (t << 6);
        if (w < NW2) bj[t] = pj2[w];
        else { bj[t].x = 0ull; bj[t].y = 0ull; }
    }

    float wmax = 0.0f;
    for (int p = wav; p < cnt; p += 4) {       // one wave per pair
        const int i = s_list[p];
        const ulonglong2* __restrict__ pi2 = (const ulonglong2*)(packed + (size_t)i * NWORDS);
        int part = 0;
        #pragma unroll
        for (int t = 0; t < 8; ++t) {
            const int w = lane + (t << 6);
            if (w < NW2) {
                const ulonglong2 a = pi2[w];
                part += __popcll(a.x & bj[t].x) + __popcll(a.y & bj[t].y);
            }
        }
        #pragma unroll
        for (int off = 32; off; off >>= 1) part += __shfl_down(part, off);
        if (lane == 0) {
            const float uni = s_sm[i] + sj - (float)part;
            const float iou = (float)part / fmaxf(uni, 1e-6f);
            d2col[(size_t)j * N_DET + i] = iou * iou;
            wmax = fmaxf(wmax, iou);
        }
    }
    if (lane == 0) s_max[wav] = wmax;
    __syncthreads();
    if (tid == 0) {
        const float c = fmaxf(fmaxf(s_max[0], s_max[1]), fmaxf(s_max[2], s_max[3]));
        comp2[j] = c * c;
    }
}

// ---------------- Kernel C: decay coef + rescore + final scores ----------------
__global__ __launch_bounds__(64) void decay_kernel(
    const float* __restrict__ d2col,
    const float* __restrict__ comp2,
    const float* __restrict__ ssum_acc,
    const float* __restrict__ cnt_acc,
    const float* __restrict__ cate_scores,
    float* __restrict__ out)
{
    const int j = blockIdx.x;
    const int lane = threadIdx.x;
    float m = 1e30f;
    for (int i = lane; i < N_DET; i += 64)
        m = fminf(m, comp2[i] - d2col[(size_t)j * N_DET + i]);
    #pragma unroll
    for (int off = 32; off; off >>= 1)
        m = fminf(m, __shfl_down(m, off));
    if (lane == 0) {
        const float C = cnt_acc[j];
        const float score = cate_scores[j] * (ssum_acc[j] / fmaxf(C, 1.0f));
        out[j] = score * expf(SIGMA * m);
    }
}

extern "C" void kernel_launch(void* const* d_in, const int* in_sizes, int n_in,
                              void* d_out, int out_size, void* d_ws, size_t ws_size,
                              hipStream_t stream) {
    const float* cate_scores = (const float*)d_in[0];
    const float* seg_x       = (const float*)d_in[1];
    const float* seg_y       = (const float*)d_in[2];
    const int*   labels      = (const int*)d_in[3];
    const int*   x_inds      = (const int*)d_in[4];
    const int*   y_inds      = (const int*)d_in[5];
    float* out = (float*)d_out;

    // workspace layout (16B-aligned blocks); total ~4.81 MB
    char* ws = (char*)d_ws;
    unsigned long long* packed = (unsigned long long*)(ws + 0);   // 500*950*8 = 3,800,000
    float* d2col    = (float*)(ws + 3800000);                     // 1,000,000
    float* ssum_acc = (float*)(ws + 4800000);                     // 2,000
    float* cnt_acc  = (float*)(ws + 4802000);                     // 2,000
    float* comp2    = (float*)(ws + 4804000);                     // 2,000

    hipMemsetAsync(ws + 4800000, 0, 4000, stream);                // ssum_acc + cnt_acc
    maskgen_kernel <<<NT, 512, 0, stream>>>(seg_x, seg_y, x_inds, y_inds,
                                            packed, ssum_acc, cnt_acc);
    pair_iou_kernel<<<N_DET, 256, 0, stream>>>(packed, cnt_acc, labels, d2col, comp2);
    decay_kernel   <<<N_DET, 64, 0, stream>>>(d2col, comp2, ssum_acc, cnt_acc,
                                              cate_scores, out);
}

// Round 5
// 173.544 us; speedup vs baseline: 3.5832x; 3.5832x over previous
//
#include <hip/hip_runtime.h>

// DecoupledSOLOHead: SOLO mask decode + Matrix NMS (gaussian), MI355X/gfx950.
//
// R5: revert R4's latency-serialized wave-per-det maskgen (533 us: 6-deep shfl
// chains + 950k same-region atomics + single-lane strided stores). Back to R3's
// tile-broadcast + thread-per-det private accumulation, with R3's sins fixed:
//  - packed is tile-major [NT][512]: maskgen wave stores 512 B contiguous
//    (R3: 8 B @ 7600-B stride = 8x write amplification, 45 MB WRITE_SIZE).
//    pair_iou eats the transpose (15 scalar u64 L2 loads/pair; only ~1.6k
//    label-gated pairs -> ~100 MB L2 traffic ~ 3 us).
//  - part_cnt array deleted: finalize recomputes cnt = popcount(packed);
//    finalize mapping lane=det (coalesced) instead of lane=tile (2000-B stride).
//  - no atomics, no memset, all writes deterministic full-width.

#define N_DET 500
#define HW    (200 * 304)        // 60800
#define TILE  64
#define NT    (HW / TILE)        // 950 tiles, exact
#define PSTR  512                // padded det stride for tile-major arrays
#define LSTR  65                 // LDS row stride: bank = (xi + p) % 32
#define MASK_THR 0.005f
#define SIGMA 2.0f

// ---------------- Kernel A: pixel-tiled broadcast decode + bit-pack ------------
__global__ __launch_bounds__(512) void maskgen_kernel(
    const float* __restrict__ seg_x, const float* __restrict__ seg_y,
    const int* __restrict__ x_inds, const int* __restrict__ y_inds,
    unsigned long long* __restrict__ packed_t,  // [NT][PSTR] tile-major
    float* __restrict__ part_sum)               // [NT][PSTR]
{
    __shared__ float sx[128 * LSTR];            // 33,280 B
    __shared__ float sy[128 * LSTR];            // 33,280 B
    const int t   = blockIdx.x;
    const int tid = threadIdx.x;
    const int base = t * TILE;

    // stage 128 rows x 64 px of each operand (each element read once chip-wide)
    for (int e = tid; e < 128 * 16; e += 512) {
        const int r  = e >> 4;
        const int c4 = (e & 15) << 2;
        const float4 vx = *(const float4*)(seg_x + (size_t)r * HW + base + c4);
        const float4 vy = *(const float4*)(seg_y + (size_t)r * HW + base + c4);
        float* dx = sx + r * LSTR + c4;
        float* dy = sy + r * LSTR + c4;
        dx[0] = vx.x; dx[1] = vx.y; dx[2] = vx.z; dx[3] = vx.w;
        dy[0] = vy.x; dy[1] = vy.y; dy[2] = vy.z; dy[3] = vy.w;
    }
    __syncthreads();

    // thread = det: private bits/sum, zero cross-lane traffic
    if (tid < N_DET) {
        const float* __restrict__ rx = sx + x_inds[tid] * LSTR;
        const float* __restrict__ ry = sy + y_inds[tid] * LSTR;
        float ssum = 0.0f;
        unsigned int lo = 0u, hi = 0u;
        #pragma unroll
        for (int p = 0; p < 32; ++p) {
            const float v = rx[p] * ry[p];
            if (v > MASK_THR) { ssum += v; lo |= (1u << p); }
        }
        #pragma unroll
        for (int p = 0; p < 32; ++p) {
            const float v = rx[32 + p] * ry[32 + p];
            if (v > MASK_THR) { ssum += v; hi |= (1u << p); }
        }
        packed_t[(size_t)t * PSTR + tid] = ((unsigned long long)hi << 32) | lo;  // coalesced
        part_sum[(size_t)t * PSTR + tid] = ssum;                                 // coalesced
    }
}

// ---------------- Kernel A2: reduce tile partials -> sum_masks, scores ---------
__global__ __launch_bounds__(512) void finalize_kernel(
    const unsigned long long* __restrict__ packed_t,
    const float* __restrict__ part_sum,
    const float* __restrict__ cate_scores,
    float* __restrict__ sum_masks, float* __restrict__ scores)
{
    __shared__ float sS[8][64];
    __shared__ int   sC[8][64];
    const int tid  = threadIdx.x;
    const int lane = tid & 63, wav = tid >> 6;
    const int n    = blockIdx.x * 64 + lane;    // 8 blocks x 64 dets
    float S = 0.0f; int C = 0;
    if (n < N_DET) {
        for (int t = wav; t < NT; t += 8) {     // lane-coalesced reads
            S += part_sum[(size_t)t * PSTR + n];
            C += __popcll(packed_t[(size_t)t * PSTR + n]);
        }
    }
    sS[wav][lane] = S; sC[wav][lane] = C;
    __syncthreads();
    if (wav == 0 && n < N_DET) {
        S = 0.0f; C = 0;
        #pragma unroll
        for (int q = 0; q < 8; ++q) { S += sS[q][lane]; C += sC[q][lane]; }
        const float sm = (float)C;
        sum_masks[n] = sm;
        scores[n] = cate_scores[n] * (S / fmaxf(sm, 1.0f));
    }
}

// ---------------- Kernel B: same-class pairwise IoU via popcount ---------------
__global__ __launch_bounds__(256) void pair_iou_kernel(
    const unsigned long long* __restrict__ packed_t,   // [NT][PSTR]
    const float* __restrict__ sum_masks,
    const int* __restrict__ labels,
    float* __restrict__ d2col,    // [N][N] col-major: d2col[j*N+i] = decay_iou^2
    float* __restrict__ comp2)    // [N] comp_iou^2
{
    const int j   = blockIdx.x;
    const int tid = threadIdx.x;
    const int lane = tid & 63, wav = tid >> 6;

    __shared__ int   s_lab[N_DET];
    __shared__ float s_sm[N_DET];
    __shared__ int   s_list[N_DET];
    __shared__ int   s_cnt;
    __shared__ float s_max[4];

    if (tid == 0) s_cnt = 0;
    for (int i = tid; i < N_DET; i += 256) {
        s_lab[i] = labels[i];
        s_sm[i]  = sum_masks[i];
        d2col[(size_t)j * N_DET + i] = 0.0f;   // ws is re-poisoned each launch
    }
    __syncthreads();

    const int   lj = s_lab[j];
    const float sj = s_sm[j];
    for (int i = tid; i < j; i += 256)
        if (s_lab[i] == lj) { const int p = atomicAdd(&s_cnt, 1); s_list[p] = i; }
    __syncthreads();
    const int cnt = s_cnt;

    // preload j's mask words (950 words across 64 lanes, 15 per lane)
    unsigned long long bj[15];
    #pragma unroll
    for (int q = 0; q < 15; ++q) {
        const int w = lane + (q << 6);
        bj[q] = (w < NT) ? packed_t[(size_t)w * PSTR + j] : 0ull;
    }

    float wmax = 0.0f;
    for (int p = wav; p < cnt; p += 4) {       // one wave per pair
        const int i = s_list[p];
        int part = 0;
        #pragma unroll
        for (int q = 0; q < 15; ++q) {
            const int w = lane + (q << 6);
            if (w < NT)
                part += __popcll(packed_t[(size_t)w * PSTR + i] & bj[q]);
        }
        #pragma unroll
        for (int off = 32; off; off >>= 1) part += __shfl_down(part, off);
        if (lane == 0) {
            const float uni = s_sm[i] + sj - (float)part;
            const float iou = (float)part / fmaxf(uni, 1e-6f);
            d2col[(size_t)j * N_DET + i] = iou * iou;
            wmax = fmaxf(wmax, iou);
        }
    }
    if (lane == 0) s_max[wav] = wmax;
    __syncthreads();
    if (tid == 0) {
        const float c = fmaxf(fmaxf(s_max[0], s_max[1]), fmaxf(s_max[2], s_max[3]));
        comp2[j] = c * c;
    }
}

// ---------------- Kernel C: decay coef + final scores --------------------------
__global__ __launch_bounds__(64) void decay_kernel(
    const float* __restrict__ d2col,
    const float* __restrict__ comp2,
    const float* __restrict__ scores,
    float* __restrict__ out)
{
    const int j = blockIdx.x;
    const int lane = threadIdx.x;
    float m = 1e30f;
    for (int i = lane; i < N_DET; i += 64)
        m = fminf(m, comp2[i] - d2col[(size_t)j * N_DET + i]);
    #pragma unroll
    for (int off = 32; off; off >>= 1)
        m = fminf(m, __shfl_down(m, off));
    if (lane == 0) out[j] = scores[j] * expf(SIGMA * m);
}

extern "C" void kernel_launch(void* const* d_in, const int* in_sizes, int n_in,
                              void* d_out, int out_size, void* d_ws, size_t ws_size,
                              hipStream_t stream) {
    const float* cate_scores = (const float*)d_in[0];
    const float* seg_x       = (const float*)d_in[1];
    const float* seg_y       = (const float*)d_in[2];
    const int*   labels      = (const int*)d_in[3];
    const int*   x_inds      = (const int*)d_in[4];
    const int*   y_inds      = (const int*)d_in[5];
    float* out = (float*)d_out;

    // workspace layout; total ~6.85 MB
    char* ws = (char*)d_ws;
    unsigned long long* packed_t = (unsigned long long*)(ws + 0);  // 950*512*8 = 3,891,200
    float* part_sum  = (float*)(ws + 3891200);                     // 950*512*4 = 1,945,600
    float* d2col     = (float*)(ws + 5836800);                     // 1,000,000
    float* scores    = (float*)(ws + 6836800);                     // 2,000
    float* comp2     = (float*)(ws + 6838800);                     // 2,000
    float* sum_masks = (float*)(ws + 6840800);                     // 2,000

    maskgen_kernel <<<NT, 512, 0, stream>>>(seg_x, seg_y, x_inds, y_inds,
                                            packed_t, part_sum);
    finalize_kernel<<<8, 512, 0, stream>>>(packed_t, part_sum, cate_scores,
                                           sum_masks, scores);
    pair_iou_kernel<<<N_DET, 256, 0, stream>>>(packed_t, sum_masks, labels,
                                               d2col, comp2);
    decay_kernel   <<<N_DET, 64, 0, stream>>>(d2col, comp2, scores, out);
}

// Round 6
// 135.980 us; speedup vs baseline: 4.5731x; 1.2762x over previous
//
#include <hip/hip_runtime.h>

// DecoupledSOLOHead: SOLO mask decode + Matrix NMS (gaussian), MI355X/gfx950.
//
// R6 vs R5 (passed, 173.5 us): finalize_kernel was a latency disaster — grid=8
// blocks = 64 waves chip-wide, 0.48% occupancy, 42-52 us doing 5.8 MB of L2
// reads with nothing to hide latency. Deleted. Its work moves to where the data
// is already flowing:
//  - pair_iou computes cnt_i/cnt_j by popcounting the bit-columns it already
//    loads (union = cnt_i + cnt_j - inter); sum_masks array deleted.
//  - pair_iou block j reduces part_sum[:,j] (950 x 4B, L2) with 256 threads and
//    writes scores[j] — runs at real occupancy inside the 500-block dispatch.
//  - maskgen (tile-major coalesced stores) and decay unchanged.

#define N_DET 500
#define HW    (200 * 304)        // 60800
#define TILE  64
#define NT    (HW / TILE)        // 950 tiles, exact
#define PSTR  512                // padded det stride for tile-major arrays
#define LSTR  65                 // LDS row stride: bank = (xi + p) % 32
#define MASK_THR 0.005f
#define SIGMA 2.0f

// ---------------- Kernel A: pixel-tiled broadcast decode + bit-pack ------------
__global__ __launch_bounds__(512) void maskgen_kernel(
    const float* __restrict__ seg_x, const float* __restrict__ seg_y,
    const int* __restrict__ x_inds, const int* __restrict__ y_inds,
    unsigned long long* __restrict__ packed_t,  // [NT][PSTR] tile-major
    float* __restrict__ part_sum)               // [NT][PSTR]
{
    __shared__ float sx[128 * LSTR];            // 33,280 B
    __shared__ float sy[128 * LSTR];            // 33,280 B
    const int t   = blockIdx.x;
    const int tid = threadIdx.x;
    const int base = t * TILE;

    // stage 128 rows x 64 px of each operand (each element read once chip-wide)
    for (int e = tid; e < 128 * 16; e += 512) {
        const int r  = e >> 4;
        const int c4 = (e & 15) << 2;
        const float4 vx = *(const float4*)(seg_x + (size_t)r * HW + base + c4);
        const float4 vy = *(const float4*)(seg_y + (size_t)r * HW + base + c4);
        float* dx = sx + r * LSTR + c4;
        float* dy = sy + r * LSTR + c4;
        dx[0] = vx.x; dx[1] = vx.y; dx[2] = vx.z; dx[3] = vx.w;
        dy[0] = vy.x; dy[1] = vy.y; dy[2] = vy.z; dy[3] = vy.w;
    }
    __syncthreads();

    // thread = det: private bits/sum, zero cross-lane traffic
    if (tid < N_DET) {
        const float* __restrict__ rx = sx + x_inds[tid] * LSTR;
        const float* __restrict__ ry = sy + y_inds[tid] * LSTR;
        float ssum = 0.0f;
        unsigned int lo = 0u, hi = 0u;
        #pragma unroll
        for (int p = 0; p < 32; ++p) {
            const float v = rx[p] * ry[p];
            if (v > MASK_THR) { ssum += v; lo |= (1u << p); }
        }
        #pragma unroll
        for (int p = 0; p < 32; ++p) {
            const float v = rx[32 + p] * ry[32 + p];
            if (v > MASK_THR) { ssum += v; hi |= (1u << p); }
        }
        packed_t[(size_t)t * PSTR + tid] = ((unsigned long long)hi << 32) | lo;  // coalesced
        part_sum[(size_t)t * PSTR + tid] = ssum;                                 // coalesced
    }
}

// ------- Kernel B: same-class IoU via popcount + per-det score, fused ----------
__global__ __launch_bounds__(256) void pair_iou_kernel(
    const unsigned long long* __restrict__ packed_t,   // [NT][PSTR]
    const float* __restrict__ part_sum,                // [NT][PSTR]
    const int* __restrict__ labels,
    const float* __restrict__ cate_scores,
    float* __restrict__ d2col,    // [N][N] col-major: d2col[j*N+i] = decay_iou^2
    float* __restrict__ comp2,    // [N] comp_iou^2
    float* __restrict__ scores)   // [N] cate * seg_score
{
    const int j   = blockIdx.x;
    const int tid = threadIdx.x;
    const int lane = tid & 63, wav = tid >> 6;

    __shared__ int   s_lab[N_DET];
    __shared__ int   s_list[N_DET];
    __shared__ int   s_cnt;
    __shared__ float s_red[4];
    __shared__ float s_max[4];

    if (tid == 0) s_cnt = 0;
    for (int i = tid; i < N_DET; i += 256) {
        s_lab[i] = labels[i];
        d2col[(size_t)j * N_DET + i] = 0.0f;   // ws is re-poisoned each launch
    }
    __syncthreads();

    const int lj = s_lab[j];
    for (int i = tid; i < j; i += 256)
        if (s_lab[i] == lj) { const int p = atomicAdd(&s_cnt, 1); s_list[p] = i; }

    // preload j's bit-column (950 words across 64 lanes, 15/lane; per-wave copy)
    unsigned long long bj[15];
    float cj_part = 0.0f;
    #pragma unroll
    for (int q = 0; q < 15; ++q) {
        const int w = lane + (q << 6);
        bj[q] = (w < NT) ? packed_t[(size_t)w * PSTR + j] : 0ull;
        cj_part += (float)__popcll(bj[q]);
    }
    #pragma unroll
    for (int off = 32; off; off >>= 1) cj_part += __shfl_down(cj_part, off);
    const float cj = __shfl(cj_part, 0);       // cnt_j, wave-uniform

    // per-det score: 256 threads reduce part_sum[:,j]
    float S = 0.0f;
    for (int t = tid; t < NT; t += 256) S += part_sum[(size_t)t * PSTR + j];
    #pragma unroll
    for (int off = 32; off; off >>= 1) S += __shfl_down(S, off);
    if (lane == 0) s_red[wav] = S;
    __syncthreads();
    if (tid == 0) {
        const float Sj = s_red[0] + s_red[1] + s_red[2] + s_red[3];
        scores[j] = cate_scores[j] * (Sj / fmaxf(cj, 1.0f));
    }
    const int cnt = s_cnt;                     // valid: sync above covers list build

    float wmax = 0.0f;
    for (int p = wav; p < cnt; p += 4) {       // one wave per pair
        const int i = s_list[p];
        int inter = 0, ci = 0;
        #pragma unroll
        for (int q = 0; q < 15; ++q) {
            const int w = lane + (q << 6);
            if (w < NT) {
                const unsigned long long a = packed_t[(size_t)w * PSTR + i];
                inter += __popcll(a & bj[q]);
                ci    += __popcll(a);
            }
        }
        #pragma unroll
        for (int off = 32; off; off >>= 1) {
            inter += __shfl_down(inter, off);
            ci    += __shfl_down(ci,    off);
        }
        if (lane == 0) {
            const float uni = (float)ci + cj - (float)inter;
            const float iou = (float)inter / fmaxf(uni, 1e-6f);
            d2col[(size_t)j * N_DET + i] = iou * iou;
            wmax = fmaxf(wmax, iou);
        }
    }
    if (lane == 0) s_max[wav] = wmax;
    __syncthreads();
    if (tid == 0) {
        const float c = fmaxf(fmaxf(s_max[0], s_max[1]), fmaxf(s_max[2], s_max[3]));
        comp2[j] = c * c;
    }
}

// ---------------- Kernel C: decay coef + final scores --------------------------
__global__ __launch_bounds__(64) void decay_kernel(
    const float* __restrict__ d2col,
    const float* __restrict__ comp2,
    const float* __restrict__ scores,
    float* __restrict__ out)
{
    const int j = blockIdx.x;
    const int lane = threadIdx.x;
    float m = 1e30f;
    for (int i = lane; i < N_DET; i += 64)
        m = fminf(m, comp2[i] - d2col[(size_t)j * N_DET + i]);
    #pragma unroll
    for (int off = 32; off; off >>= 1)
        m = fminf(m, __shfl_down(m, off));
    if (lane == 0) out[j] = scores[j] * expf(SIGMA * m);
}

extern "C" void kernel_launch(void* const* d_in, const int* in_sizes, int n_in,
                              void* d_out, int out_size, void* d_ws, size_t ws_size,
                              hipStream_t stream) {
    const float* cate_scores = (const float*)d_in[0];
    const float* seg_x       = (const float*)d_in[1];
    const float* seg_y       = (const float*)d_in[2];
    const int*   labels      = (const int*)d_in[3];
    const int*   x_inds      = (const int*)d_in[4];
    const int*   y_inds      = (const int*)d_in[5];
    float* out = (float*)d_out;

    // workspace layout; total ~6.84 MB
    char* ws = (char*)d_ws;
    unsigned long long* packed_t = (unsigned long long*)(ws + 0);  // 950*512*8 = 3,891,200
    float* part_sum = (float*)(ws + 3891200);                      // 950*512*4 = 1,945,600
    float* d2col    = (float*)(ws + 5836800);                      // 1,000,000
    float* scores   = (float*)(ws + 6836800);                      // 2,000
    float* comp2    = (float*)(ws + 6838800);                      // 2,000

    maskgen_kernel <<<NT, 512, 0, stream>>>(seg_x, seg_y, x_inds, y_inds,
                                            packed_t, part_sum);
    pair_iou_kernel<<<N_DET, 256, 0, stream>>>(packed_t, part_sum, labels,
                                               cate_scores, d2col, comp2, scores);
    decay_kernel   <<<N_DET, 64, 0, stream>>>(d2col, comp2, scores, out);
}

// Round 7
// 130.561 us; speedup vs baseline: 4.7629x; 1.0415x over previous
//
#include <hip/hip_runtime.h>

// DecoupledSOLOHead: SOLO mask decode + Matrix NMS (gaussian), MI355X/gfx950.
//
// R7 vs R6 (passed, 136.0 us; fixed harness floor ~65 us, our kernels ~65 us):
//  - maskgen: LSTR 65->68 (16B-aligned rows), b128 LDS reads/writes — 32 vector
//    wave-instrs per det-row instead of 128 scalar b32; start-bank (4xi+4k)%32
//    spreads across 8 bank-quads ≈ the 8-cyc floor for 1KB/instr.
//  - new 120-block LDS tile-transpose (64x64): packed_t/part_sum -> det-major
//    packed_d[500][950] + part_sumT[500][950], everything coalesced (~12 MB).
//  - pair_iou reads det-major: bj preload, AND-popcount, score-reduce all
//    coalesced streams (kills R6's ~250 MB of 64B-line scalar L2 gathers).

#define N_DET 500
#define HW    (200 * 304)        // 60800
#define TILE  64
#define NT    (HW / TILE)        // 950 tiles, exact
#define PSTR  512                // det stride in tile-major arrays
#define DSTR  950                // tile stride in det-major arrays (950*8 % 16 == 0)
#define NW2   (NT / 2)           // 475 ulonglong2 granules
#define LSTR  68                 // LDS row stride (floats), 16B-aligned rows
#define MASK_THR 0.005f
#define SIGMA 2.0f

// ---------------- Kernel A: pixel-tiled broadcast decode + bit-pack ------------
__global__ __launch_bounds__(512) void maskgen_kernel(
    const float* __restrict__ seg_x, const float* __restrict__ seg_y,
    const int* __restrict__ x_inds, const int* __restrict__ y_inds,
    unsigned long long* __restrict__ packed_t,  // [NT][PSTR] tile-major
    float* __restrict__ part_sum)               // [NT][PSTR]
{
    __shared__ __align__(16) float sx[128 * LSTR];   // 34,816 B
    __shared__ __align__(16) float sy[128 * LSTR];   // 34,816 B
    const int t   = blockIdx.x;
    const int tid = threadIdx.x;
    const int base = t * TILE;

    // stage 128 rows x 64 px of each operand; b128 both sides
    for (int e = tid; e < 128 * 16; e += 512) {
        const int r  = e >> 4;
        const int c4 = (e & 15) << 2;
        *(float4*)(sx + r * LSTR + c4) = *(const float4*)(seg_x + (size_t)r * HW + base + c4);
        *(float4*)(sy + r * LSTR + c4) = *(const float4*)(seg_y + (size_t)r * HW + base + c4);
    }
    __syncthreads();

    // thread = det: 16+16 b128 LDS reads, private bits/sum
    if (tid < N_DET) {
        const float* __restrict__ rx = sx + x_inds[tid] * LSTR;
        const float* __restrict__ ry = sy + y_inds[tid] * LSTR;
        float ssum = 0.0f;
        unsigned int lo = 0u, hi = 0u;
        #pragma unroll
        for (int k = 0; k < 8; ++k) {
            const float4 xv = *(const float4*)(rx + (k << 2));
            const float4 yv = *(const float4*)(ry + (k << 2));
            const float p0 = xv.x * yv.x, p1 = xv.y * yv.y,
                        p2 = xv.z * yv.z, p3 = xv.w * yv.w;
            if (p0 > MASK_THR) { ssum += p0; lo |= 1u << (4 * k); }
            if (p1 > MASK_THR) { ssum += p1; lo |= 1u << (4 * k + 1); }
            if (p2 > MASK_THR) { ssum += p2; lo |= 1u << (4 * k + 2); }
            if (p3 > MASK_THR) { ssum += p3; lo |= 1u << (4 * k + 3); }
        }
        #pragma unroll
        for (int k = 0; k < 8; ++k) {
            const float4 xv = *(const float4*)(rx + 32 + (k << 2));
            const float4 yv = *(const float4*)(ry + 32 + (k << 2));
            const float p0 = xv.x * yv.x, p1 = xv.y * yv.y,
                        p2 = xv.z * yv.z, p3 = xv.w * yv.w;
            if (p0 > MASK_THR) { ssum += p0; hi |= 1u << (4 * k); }
            if (p1 > MASK_THR) { ssum += p1; hi |= 1u << (4 * k + 1); }
            if (p2 > MASK_THR) { ssum += p2; hi |= 1u << (4 * k + 2); }
            if (p3 > MASK_THR) { ssum += p3; hi |= 1u << (4 * k + 3); }
        }
        packed_t[(size_t)t * PSTR + tid] = ((unsigned long long)hi << 32) | lo;  // coalesced
        part_sum[(size_t)t * PSTR + tid] = ssum;                                 // coalesced
    }
}

// ------- Kernel T: 64x64 LDS tile transpose -> det-major layouts ---------------
__global__ __launch_bounds__(256) void transpose_kernel(
    const unsigned long long* __restrict__ packed_t,  // [NT][PSTR]
    const float* __restrict__ part_sum,               // [NT][PSTR]
    unsigned long long* __restrict__ packed_d,        // [N_DET][DSTR]
    float* __restrict__ part_sumT)                    // [N_DET][DSTR]
{
    __shared__ unsigned long long tp[64 * 65];        // 33,280 B
    __shared__ float              ts[64 * 65];        // 16,640 B
    const int t0  = blockIdx.x * 64;                  // 15 tiles -> 960 (>=950)
    const int d0  = blockIdx.y * 64;                  // 8 tiles -> 512
    const int tid = threadIdx.x;
    const int lane = tid & 63, wav = tid >> 6;

    #pragma unroll
    for (int k = 0; k < 16; ++k) {
        const int r  = (k << 2) + wav;                // 0..63
        const int gt = t0 + r;
        unsigned long long v = 0ull; float s = 0.0f;
        if (gt < NT) {
            v = packed_t[(size_t)gt * PSTR + d0 + lane];   // 512 B coalesced
            s = part_sum[(size_t)gt * PSTR + d0 + lane];
        }
        tp[r * 65 + lane] = v;
        ts[r * 65 + lane] = s;
    }
    __syncthreads();
    const int gt = t0 + lane;
    #pragma unroll
    for (int k = 0; k < 16; ++k) {
        const int m = (k << 2) + wav;
        const int d = d0 + m;
        if (gt < NT && d < N_DET) {
            packed_d [(size_t)d * DSTR + gt] = tp[lane * 65 + m];  // coalesced
            part_sumT[(size_t)d * DSTR + gt] = ts[lane * 65 + m];
        }
    }
}

// ------- Kernel B: same-class IoU via popcount + per-det score, fused ----------
__global__ __launch_bounds__(256) void pair_iou_kernel(
    const unsigned long long* __restrict__ packed_d,   // [N_DET][DSTR]
    const float* __restrict__ part_sumT,               // [N_DET][DSTR]
    const int* __restrict__ labels,
    const float* __restrict__ cate_scores,
    float* __restrict__ d2col,    // [N][N] col-major: d2col[j*N+i] = decay_iou^2
    float* __restrict__ comp2,    // [N] comp_iou^2
    float* __restrict__ scores)   // [N] cate * seg_score
{
    const int j   = blockIdx.x;
    const int tid = threadIdx.x;
    const int lane = tid & 63, wav = tid >> 6;

    __shared__ int   s_lab[N_DET];
    __shared__ int   s_list[N_DET];
    __shared__ int   s_cnt;
    __shared__ float s_red[4];
    __shared__ float s_max[4];

    if (tid == 0) s_cnt = 0;
    for (int i = tid; i < N_DET; i += 256) {
        s_lab[i] = labels[i];
        d2col[(size_t)j * N_DET + i] = 0.0f;   // ws is re-poisoned each launch
    }
    __syncthreads();

    const int lj = s_lab[j];
    for (int i = tid; i < j; i += 256)
        if (s_lab[i] == lj) { const int p = atomicAdd(&s_cnt, 1); s_list[p] = i; }

    // preload j's bit-row, coalesced ull2 (475 granules across 64 lanes, 8/lane)
    const ulonglong2* __restrict__ pj2 = (const ulonglong2*)(packed_d + (size_t)j * DSTR);
    ulonglong2 bj[8];
    float cj_part = 0.0f;
    #pragma unroll
    for (int q = 0; q < 8; ++q) {
        const int w = lane + (q << 6);
        if (w < NW2) {
            bj[q] = pj2[w];
            cj_part += (float)(__popcll(bj[q].x) + __popcll(bj[q].y));
        } else { bj[q].x = 0ull; bj[q].y = 0ull; }
    }
    #pragma unroll
    for (int off = 32; off; off >>= 1) cj_part += __shfl_down(cj_part, off);
    const float cj = __shfl(cj_part, 0);       // cnt_j, wave-uniform

    // per-det score: 256 threads stream part_sumT[j], coalesced
    float S = 0.0f;
    for (int t = tid; t < NT; t += 256) S += part_sumT[(size_t)j * DSTR + t];
    #pragma unroll
    for (int off = 32; off; off >>= 1) S += __shfl_down(S, off);
    if (lane == 0) s_red[wav] = S;
    __syncthreads();
    if (tid == 0) {
        const float Sj = s_red[0] + s_red[1] + s_red[2] + s_red[3];
        scores[j] = cate_scores[j] * (Sj / fmaxf(cj, 1.0f));
    }
    const int cnt = s_cnt;                     // sync above covers list build

    float wmax = 0.0f;
    for (int p = wav; p < cnt; p += 4) {       // one wave per pair
        const int i = s_list[p];
        const ulonglong2* __restrict__ pi2 = (const ulonglong2*)(packed_d + (size_t)i * DSTR);
        int inter = 0, ci = 0;
        #pragma unroll
        for (int q = 0; q < 8; ++q) {
            const int w = lane + (q << 6);
            if (w < NW2) {
                const ulonglong2 a = pi2[w];   // coalesced 1 KB/instr
                inter += __popcll(a.x & bj[q].x) + __popcll(a.y & bj[q].y);
                ci    += __popcll(a.x) + __popcll(a.y);
            }
        }
        #pragma unroll
        for (int off = 32; off; off >>= 1) {
            inter += __shfl_down(inter, off);
            ci    += __shfl_down(ci,    off);
        }
        if (lane == 0) {
            const float uni = (float)ci + cj - (float)inter;
            const float iou = (float)inter / fmaxf(uni, 1e-6f);
            d2col[(size_t)j * N_DET + i] = iou * iou;
            wmax = fmaxf(wmax, iou);
        }
    }
    if (lane == 0) s_max[wav] = wmax;
    __syncthreads();
    if (tid == 0) {
        const float c = fmaxf(fmaxf(s_max[0], s_max[1]), fmaxf(s_max[2], s_max[3]));
        comp2[j] = c * c;
    }
}

// ---------------- Kernel C: decay coef + final scores --------------------------
__global__ __launch_bounds__(64) void decay_kernel(
    const float* __restrict__ d2col,
    const float* __restrict__ comp2,
    const float* __restrict__ scores,
    float* __restrict__ out)
{
    const int j = blockIdx.x;
    const int lane = threadIdx.x;
    float m = 1e30f;
    for (int i = lane; i < N_DET; i += 64)
        m = fminf(m, comp2[i] - d2col[(size_t)j * N_DET + i]);
    #pragma unroll
    for (int off = 32; off; off >>= 1)
        m = fminf(m, __shfl_down(m, off));
    if (lane == 0) out[j] = scores[j] * expf(SIGMA * m);
}

extern "C" void kernel_launch(void* const* d_in, const int* in_sizes, int n_in,
                              void* d_out, int out_size, void* d_ws, size_t ws_size,
                              hipStream_t stream) {
    const float* cate_scores = (const float*)d_in[0];
    const float* seg_x       = (const float*)d_in[1];
    const float* seg_y       = (const float*)d_in[2];
    const int*   labels      = (const int*)d_in[3];
    const int*   x_inds      = (const int*)d_in[4];
    const int*   y_inds      = (const int*)d_in[5];
    float* out = (float*)d_out;

    // workspace layout (16B-aligned); total ~12.54 MB
    char* ws = (char*)d_ws;
    unsigned long long* packed_t = (unsigned long long*)(ws + 0);        // 950*512*8 = 3,891,200
    float* part_sum  = (float*)(ws + 3891200);                           // 950*512*4 = 1,945,600
    unsigned long long* packed_d = (unsigned long long*)(ws + 5836800);  // 500*950*8 = 3,800,000
    float* part_sumT = (float*)(ws + 9636800);                           // 500*950*4 = 1,900,000
    float* d2col     = (float*)(ws + 11536800);                          // 1,000,000
    float* scores    = (float*)(ws + 12536800);                          // 2,000
    float* comp2     = (float*)(ws + 12538800);                          // 2,000

    maskgen_kernel  <<<NT, 512, 0, stream>>>(seg_x, seg_y, x_inds, y_inds,
                                             packed_t, part_sum);
    transpose_kernel<<<dim3(15, 8), 256, 0, stream>>>(packed_t, part_sum,
                                                      packed_d, part_sumT);
    pair_iou_kernel <<<N_DET, 256, 0, stream>>>(packed_d, part_sumT, labels,
                                                cate_scores, d2col, comp2, scores);
    decay_kernel    <<<N_DET, 64, 0, stream>>>(d2col, comp2, scores, out);
}

// Round 8
// 125.307 us; speedup vs baseline: 4.9626x; 1.0419x over previous
//
#include <hip/hip_runtime.h>

// DecoupledSOLOHead: SOLO mask decode + Matrix NMS (gaussian), MI355X/gfx950.
//
// R8 vs R7 (passed, 130.6 us; top-5 all harness 256MiB ws-poison fills):
//  - maskgen: conflict-free LDS gather by construction. LSTR=64 (every row
//    starts at bank-quad 0) + lane-rotated read phase f=(k+tid)&15 -> each b128
//    wave-instr lands exactly 8 lanes per bank-quad regardless of the random
//    row indices. Bits via single variable shift w |= nib << 4f (pixel-order
//    u64, layout identical to R7's).
//  - transpose: 512 threads (8-iter loops) for 2x waves in flight on the
//    small 120-block latency-bound grid.
//  - pair_iou / decay unchanged from R7.

#define N_DET 500
#define HW    (200 * 304)        // 60800
#define TILE  64
#define NT    (HW / TILE)        // 950 tiles, exact
#define PSTR  512                // det stride in tile-major arrays
#define DSTR  950                // tile stride in det-major arrays
#define NW2   (NT / 2)           // 475 ulonglong2 granules
#define MASK_THR 0.005f
#define SIGMA 2.0f

// ---------------- Kernel A: pixel-tiled broadcast decode + bit-pack ------------
__global__ __launch_bounds__(512) void maskgen_kernel(
    const float* __restrict__ seg_x, const float* __restrict__ seg_y,
    const int* __restrict__ x_inds, const int* __restrict__ y_inds,
    unsigned long long* __restrict__ packed_t,  // [NT][PSTR] tile-major
    float* __restrict__ part_sum)               // [NT][PSTR]
{
    __shared__ __align__(16) float sx[128 * 64];     // 32,768 B
    __shared__ __align__(16) float sy[128 * 64];     // 32,768 B
    const int t   = blockIdx.x;
    const int tid = threadIdx.x;
    const int base = t * TILE;

    // stage 128 rows x 64 px of each operand; b128 both sides, bank-balanced
    for (int e = tid; e < 128 * 16; e += 512) {
        const int r  = e >> 4;
        const int c4 = (e & 15) << 2;
        *(float4*)(sx + (r << 6) + c4) = *(const float4*)(seg_x + (size_t)r * HW + base + c4);
        *(float4*)(sy + (r << 6) + c4) = *(const float4*)(seg_y + (size_t)r * HW + base + c4);
    }
    __syncthreads();

    // thread = det; lane-rotated phase makes every b128 read conflict-free
    if (tid < N_DET) {
        const float4* __restrict__ rx4 = (const float4*)(sx + (x_inds[tid] << 6));
        const float4* __restrict__ ry4 = (const float4*)(sy + (y_inds[tid] << 6));
        float ssum = 0.0f;
        unsigned long long w = 0ull;
        #pragma unroll
        for (int k = 0; k < 16; ++k) {
            const int f = (k + tid) & 15;            // 8 lanes per bank-quad
            const float4 xv = rx4[f];
            const float4 yv = ry4[f];
            const float p0 = xv.x * yv.x, p1 = xv.y * yv.y,
                        p2 = xv.z * yv.z, p3 = xv.w * yv.w;
            const int b0 = p0 > MASK_THR, b1 = p1 > MASK_THR,
                      b2 = p2 > MASK_THR, b3 = p3 > MASK_THR;
            ssum += (b0 ? p0 : 0.0f) + (b1 ? p1 : 0.0f)
                  + (b2 ? p2 : 0.0f) + (b3 ? p3 : 0.0f);
            const unsigned int nib = (unsigned)(b0 | (b1 << 1) | (b2 << 2) | (b3 << 3));
            w |= (unsigned long long)nib << (f << 2);  // pixel-order bits
        }
        packed_t[(size_t)t * PSTR + tid] = w;          // coalesced
        part_sum[(size_t)t * PSTR + tid] = ssum;       // coalesced
    }
}

// ------- Kernel T: 64x64 LDS tile transpose -> det-major layouts ---------------
__global__ __launch_bounds__(512) void transpose_kernel(
    const unsigned long long* __restrict__ packed_t,  // [NT][PSTR]
    const float* __restrict__ part_sum,               // [NT][PSTR]
    unsigned long long* __restrict__ packed_d,        // [N_DET][DSTR]
    float* __restrict__ part_sumT)                    // [N_DET][DSTR]
{
    __shared__ unsigned long long tp[64 * 65];        // 33,280 B
    __shared__ float              ts[64 * 65];        // 16,640 B
    const int t0  = blockIdx.x * 64;                  // 15 x-tiles -> 960 (>=950)
    const int d0  = blockIdx.y * 64;                  // 8 y-tiles  -> 512
    const int tid = threadIdx.x;
    const int lane = tid & 63, wav = tid >> 6;        // 8 waves

    #pragma unroll
    for (int k = 0; k < 8; ++k) {
        const int r  = (k << 3) + wav;                // 0..63
        const int gt = t0 + r;
        unsigned long long v = 0ull; float s = 0.0f;
        if (gt < NT) {
            v = packed_t[(size_t)gt * PSTR + d0 + lane];   // 512 B coalesced
            s = part_sum[(size_t)gt * PSTR + d0 + lane];
        }
        tp[r * 65 + lane] = v;
        ts[r * 65 + lane] = s;
    }
    __syncthreads();
    const int gt = t0 + lane;
    #pragma unroll
    for (int k = 0; k < 8; ++k) {
        const int m = (k << 3) + wav;
        const int d = d0 + m;
        if (gt < NT && d < N_DET) {
            packed_d [(size_t)d * DSTR + gt] = tp[lane * 65 + m];  // coalesced
            part_sumT[(size_t)d * DSTR + gt] = ts[lane * 65 + m];
        }
    }
}

// ------- Kernel B: same-class IoU via popcount + per-det score, fused ----------
__global__ __launch_bounds__(256) void pair_iou_kernel(
    const unsigned long long* __restrict__ packed_d,   // [N_DET][DSTR]
    const float* __restrict__ part_sumT,               // [N_DET][DSTR]
    const int* __restrict__ labels,
    const float* __restrict__ cate_scores,
    float* __restrict__ d2col,    // [N][N] col-major: d2col[j*N+i] = decay_iou^2
    float* __restrict__ comp2,    // [N] comp_iou^2
    float* __restrict__ scores)   // [N] cate * seg_score
{
    const int j   = blockIdx.x;
    const int tid = threadIdx.x;
    const int lane = tid & 63, wav = tid >> 6;

    __shared__ int   s_lab[N_DET];
    __shared__ int   s_list[N_DET];
    __shared__ int   s_cnt;
    __shared__ float s_red[4];
    __shared__ float s_max[4];

    if (tid == 0) s_cnt = 0;
    for (int i = tid; i < N_DET; i += 256) {
        s_lab[i] = labels[i];
        d2col[(size_t)j * N_DET + i] = 0.0f;   // ws is re-poisoned each launch
    }
    __syncthreads();

    const int lj = s_lab[j];
    for (int i = tid; i < j; i += 256)
        if (s_lab[i] == lj) { const int p = atomicAdd(&s_cnt, 1); s_list[p] = i; }

    // preload j's bit-row, coalesced ull2 (475 granules across 64 lanes, 8/lane)
    const ulonglong2* __restrict__ pj2 = (const ulonglong2*)(packed_d + (size_t)j * DSTR);
    ulonglong2 bj[8];
    float cj_part = 0.0f;
    #pragma unroll
    for (int q = 0; q < 8; ++q) {
        const int w = lane + (q << 6);
        if (w < NW2) {
            bj[q] = pj2[w];
            cj_part += (float)(__popcll(bj[q].x) + __popcll(bj[q].y));
        } else { bj[q].x = 0ull; bj[q].y = 0ull; }
    }
    #pragma unroll
    for (int off = 32; off; off >>= 1) cj_part += __shfl_down(cj_part, off);
    const float cj = __shfl(cj_part, 0);       // cnt_j, wave-uniform

    // per-det score: 256 threads stream part_sumT[j], coalesced
    float S = 0.0f;
    for (int t = tid; t < NT; t += 256) S += part_sumT[(size_t)j * DSTR + t];
    #pragma unroll
    for (int off = 32; off; off >>= 1) S += __shfl_down(S, off);
    if (lane == 0) s_red[wav] = S;
    __syncthreads();
    if (tid == 0) {
        const float Sj = s_red[0] + s_red[1] + s_red[2] + s_red[3];
        scores[j] = cate_scores[j] * (Sj / fmaxf(cj, 1.0f));
    }
    const int cnt = s_cnt;                     // sync above covers list build

    float wmax = 0.0f;
    for (int p = wav; p < cnt; p += 4) {       // one wave per pair
        const int i = s_list[p];
        const ulonglong2* __restrict__ pi2 = (const ulonglong2*)(packed_d + (size_t)i * DSTR);
        int inter = 0, ci = 0;
        #pragma unroll
        for (int q = 0; q < 8; ++q) {
            const int w = lane + (q << 6);
            if (w < NW2) {
                const ulonglong2 a = pi2[w];   // coalesced 1 KB/instr
                inter += __popcll(a.x & bj[q].x) + __popcll(a.y & bj[q].y);
                ci    += __popcll(a.x) + __popcll(a.y);
            }
        }
        #pragma unroll
        for (int off = 32; off; off >>= 1) {
            inter += __shfl_down(inter, off);
            ci    += __shfl_down(ci,    off);
        }
        if (lane == 0) {
            const float uni = (float)ci + cj - (float)inter;
            const float iou = (float)inter / fmaxf(uni, 1e-6f);
            d2col[(size_t)j * N_DET + i] = iou * iou;
            wmax = fmaxf(wmax, iou);
        }
    }
    if (lane == 0) s_max[wav] = wmax;
    __syncthreads();
    if (tid == 0) {
        const float c = fmaxf(fmaxf(s_max[0], s_max[1]), fmaxf(s_max[2], s_max[3]));
        comp2[j] = c * c;
    }
}

// ---------------- Kernel C: decay coef + final scores --------------------------
__global__ __launch_bounds__(64) void decay_kernel(
    const float* __restrict__ d2col,
    const float* __restrict__ comp2,
    const float* __restrict__ scores,
    float* __restrict__ out)
{
    const int j = blockIdx.x;
    const int lane = threadIdx.x;
    float m = 1e30f;
    for (int i = lane; i < N_DET; i += 64)
        m = fminf(m, comp2[i] - d2col[(size_t)j * N_DET + i]);
    #pragma unroll
    for (int off = 32; off; off >>= 1)
        m = fminf(m, __shfl_down(m, off));
    if (lane == 0) out[j] = scores[j] * expf(SIGMA * m);
}

extern "C" void kernel_launch(void* const* d_in, const int* in_sizes, int n_in,
                              void* d_out, int out_size, void* d_ws, size_t ws_size,
                              hipStream_t stream) {
    const float* cate_scores = (const float*)d_in[0];
    const float* seg_x       = (const float*)d_in[1];
    const float* seg_y       = (const float*)d_in[2];
    const int*   labels      = (const int*)d_in[3];
    const int*   x_inds      = (const int*)d_in[4];
    const int*   y_inds      = (const int*)d_in[5];
    float* out = (float*)d_out;

    // workspace layout (16B-aligned); total ~12.54 MB
    char* ws = (char*)d_ws;
    unsigned long long* packed_t = (unsigned long long*)(ws + 0);        // 950*512*8 = 3,891,200
    float* part_sum  = (float*)(ws + 3891200);                           // 950*512*4 = 1,945,600
    unsigned long long* packed_d = (unsigned long long*)(ws + 5836800);  // 500*950*8 = 3,800,000
    float* part_sumT = (float*)(ws + 9636800);                           // 500*950*4 = 1,900,000
    float* d2col     = (float*)(ws + 11536800);                          // 1,000,000
    float* scores    = (float*)(ws + 12536800);                          // 2,000
    float* comp2     = (float*)(ws + 12538800);                          // 2,000

    maskgen_kernel  <<<NT, 512, 0, stream>>>(seg_x, seg_y, x_inds, y_inds,
                                             packed_t, part_sum);
    transpose_kernel<<<dim3(15, 8), 512, 0, stream>>>(packed_t, part_sum,
                                                      packed_d, part_sumT);
    pair_iou_kernel <<<N_DET, 256, 0, stream>>>(packed_d, part_sumT, labels,
                                                cate_scores, d2col, comp2, scores);
    decay_kernel    <<<N_DET, 64, 0, stream>>>(d2col, comp2, scores, out);
}